// Round 8
// baseline (156.937 us; speedup 1.0000x reference)
//
#include <hip/hip_runtime.h>
#include <hip/hip_bf16.h>

#define NPTS 524288
#define DIM 256
#define KC 64

typedef __attribute__((ext_vector_type(8))) short bf16x8;
typedef __attribute__((ext_vector_type(4))) float f32x4;

static __device__ __forceinline__ short f2bf(float f) {
  return __builtin_bit_cast(short, __float2bfloat16(f));  // RNE; pairs fuse to cvt_pk
}

// Single fused kernel. Block = 4 waves, 64 rows (16/wave), all 64 clusters.
// Phase 0: build B (bf16, slot-permuted + XOR-swizzled) and c2 (fp32) in LDS
//          directly from the fp32 clusters array (64 KB L2-broadcast reads).
//          B slot s holds cluster 4*(s%16)+s/16; granule m of slot s at byte
//          s*512 + ((m ^ (s&7))<<4) -> ds_read_b128 conflict-free (R2-R7).
// Phase 1: R4 body verbatim (best measured: 131.2 us): A global->register,
//          depth-2 prefetch over 3 rotating buffer pairs, MFMA dot, fused
//          Student-t epilogue, coalesced float4 stores.
__global__ __launch_bounds__(256, 4)
void cluster_q(const float* __restrict__ A, const float* __restrict__ C,
               float* __restrict__ out) {
  __shared__ __align__(16) char lds[33024];  // 32 KiB B image + 256 B c2
  float* c2s = (float*)(lds + 32768);
  const int tid = threadIdx.x;
  const int lane = tid & 63;
  const int w = tid >> 6;
  const int l15 = lane & 15;
  const int g = lane >> 4;
  const long brow = (long)blockIdx.x * 64;

  // lane (l15,g) owns row (w*16+l15), bytes ks*128 + g*32 .. +32 per K-step
  const char* Ap = (const char*)A + (brow + w * 16 + l15) * 1024 + g * 32;

  // ---- phase 0: B image + c2 from clusters (L2-resident after first blocks)
  {
    const int k = tid >> 2;                    // cluster 0..63
    const int qt = tid & 3;                    // quarter of the row
    const int slot = 16 * (k & 3) + (k >> 2);  // permuted slot
    const float4* src = (const float4*)(C + k * DIM + qt * 64);
    float s = 0.f;
#pragma unroll
    for (int i = 0; i < 8; ++i) {              // granule m = qt*8 + i
      float4 u0 = src[2 * i];
      float4 u1 = src[2 * i + 1];
      float vv[8] = {u0.x, u0.y, u0.z, u0.w, u1.x, u1.y, u1.z, u1.w};
      bf16x8 h;
#pragma unroll
      for (int j2 = 0; j2 < 8; ++j2) {
        s = fmaf(vv[j2], vv[j2], s);
        h[j2] = f2bf(vv[j2]);
      }
      const int m = qt * 8 + i;
      *(bf16x8*)(lds + slot * 512 + ((m ^ (slot & 7)) << 4)) = h;
    }
    s += __shfl_xor(s, 1);  // quarters of cluster k live in 4 adjacent lanes
    s += __shfl_xor(s, 2);
    if (qt == 0) c2s[k] = s;
  }
  __syncthreads();  // B + c2 resident; only barrier in the block

  // ---- phase 1: R4 body
  float4 b0a = *(const float4*)(Ap + 0 * 128);
  float4 b0b = *(const float4*)(Ap + 0 * 128 + 16);
  float4 b1a = *(const float4*)(Ap + 1 * 128);
  float4 b1b = *(const float4*)(Ap + 1 * 128 + 16);
  float4 b2a, b2b;

  f32x4 acc[4];
#pragma unroll
  for (int t = 0; t < 4; ++t) acc[t] = (f32x4){0.f, 0.f, 0.f, 0.f};
  float x2l = 0.f;

#define KSTEP(ks, CA, CB, PA, PB)                                            \
  do {                                                                       \
    float vv[8] = {CA.x, CA.y, CA.z, CA.w, CB.x, CB.y, CB.z, CB.w};          \
    if ((ks) + 2 < 8) {                                                      \
      PA = *(const float4*)(Ap + ((ks) + 2) * 128);                          \
      PB = *(const float4*)(Ap + ((ks) + 2) * 128 + 16);                     \
    }                                                                        \
    bf16x8 af;                                                               \
    _Pragma("unroll") for (int j2 = 0; j2 < 8; ++j2) {                       \
      x2l = fmaf(vv[j2], vv[j2], x2l);                                       \
      af[j2] = f2bf(vv[j2]);                                                 \
    }                                                                        \
    _Pragma("unroll") for (int t = 0; t < 4; ++t) {                          \
      int slot = l15 + 16 * t;                                               \
      bf16x8 bf = *(const bf16x8*)(lds + slot * 512 +                        \
                                   ((((ks) * 4 + g) ^ (slot & 7)) << 4));    \
      acc[t] = __builtin_amdgcn_mfma_f32_16x16x32_bf16(af, bf, acc[t], 0, 0, 0); \
    }                                                                        \
  } while (0)

  // buffers rotate mod 3; prefetch target (ks+2)%3 never aliases ks or ks+1
  KSTEP(0, b0a, b0b, b2a, b2b);
  KSTEP(1, b1a, b1b, b0a, b0b);
  KSTEP(2, b2a, b2b, b1a, b1b);
  KSTEP(3, b0a, b0b, b2a, b2b);
  KSTEP(4, b1a, b1b, b0a, b0b);
  KSTEP(5, b2a, b2b, b1a, b1b);
  KSTEP(6, b0a, b0b, b0a, b0b);  // ks+2 >= 8: no prefetch
  KSTEP(7, b1a, b1b, b0a, b0b);  // ks+2 >= 8: no prefetch
#undef KSTEP

  // ---- epilogue
  x2l += __shfl_xor(x2l, 16);
  x2l += __shfl_xor(x2l, 32);  // full ||x||^2 for row l15, replicated across g
  float x2r[4];
#pragma unroll
  for (int r = 0; r < 4; ++r) x2r[r] = __shfl(x2l, g * 4 + r);

  float4 c2v = *(const float4*)(c2s + 4 * l15);  // clusters 4*l15 .. +3 (== t)
  float c2a[4] = {c2v.x, c2v.y, c2v.z, c2v.w};

  float qv[4][4];
  float rsum[4] = {0.f, 0.f, 0.f, 0.f};
#pragma unroll
  for (int t = 0; t < 4; ++t) {
#pragma unroll
    for (int r = 0; r < 4; ++r) {
      float d2 = fmaxf(x2r[r] + c2a[t] - 2.0f * acc[t][r], 0.f);
      float qq = __builtin_amdgcn_rcpf(1.0f + d2);  // ALPHA=1, exponent 1
      qv[t][r] = qq;
      rsum[r] += qq;
    }
  }
#pragma unroll
  for (int r = 0; r < 4; ++r) {
    rsum[r] += __shfl_xor(rsum[r], 1);
    rsum[r] += __shfl_xor(rsum[r], 2);
    rsum[r] += __shfl_xor(rsum[r], 4);
    rsum[r] += __shfl_xor(rsum[r], 8);
    float inv = __builtin_amdgcn_rcpf(rsum[r]);
    long orow = brow + w * 16 + g * 4 + r;
    float4 o4 = {qv[0][r] * inv, qv[1][r] * inv, qv[2][r] * inv, qv[3][r] * inv};
    *(float4*)(out + orow * 64 + 4 * l15) = o4;  // lane holds clusters 4*l15..+3
  }
}

extern "C" void kernel_launch(void* const* d_in, const int* in_sizes, int n_in,
                              void* d_out, int out_size, void* d_ws, size_t ws_size,
                              hipStream_t stream) {
  const float* inputs = (const float*)d_in[0];
  const float* clusters = (const float*)d_in[1];
  float* out = (float*)d_out;
  cluster_q<<<NPTS / 64, 256, 0, stream>>>(inputs, clusters, out);
}

// Round 9
// 130.946 us; speedup vs baseline: 1.1985x; 1.1985x over previous
//
#include <hip/hip_runtime.h>
#include <hip/hip_bf16.h>

#define NPTS 524288
#define DIM 256
#define KC 64

typedef __attribute__((ext_vector_type(8))) short bf16x8;
typedef __attribute__((ext_vector_type(4))) float f32x4;

typedef __attribute__((address_space(1))) const unsigned int GUI;
typedef __attribute__((address_space(3))) unsigned int LUI;

static __device__ __forceinline__ void gload16(const void* g, void* l) {
  __builtin_amdgcn_global_load_lds((GUI*)g, (LUI*)l, 16, 0, 0);
}

static __device__ __forceinline__ ushort f32_to_bf16_rne(float f) {
  unsigned int b = __builtin_bit_cast(unsigned int, f);
  b += 0x7FFFu + ((b >> 16) & 1u);   // RNE; inputs finite
  return (ushort)(b >> 16);
}

static __device__ __forceinline__ short f2bf(float f) {
  return __builtin_bit_cast(short, __float2bfloat16(f));  // pairs fuse to cvt_pk
}

// ws image (32 KiB): slot s holds cluster 4*(s%16)+s/16; 16-B granule m of slot s
// lives at byte s*512 + ((m ^ (s&7))<<4). c2 (natural cluster order) at +32768.
__global__ void prep_clusters(const float* __restrict__ C,
                              char* __restrict__ cb,
                              float* __restrict__ c2) {
  const int w = threadIdx.x >> 6;
  const int lane = threadIdx.x & 63;
  const int k = blockIdx.x * 8 + w * 2 + (lane >> 5);  // cluster
  const int m = lane & 31;                             // 16-B granule (8 elems)
  const float* src = C + k * DIM + m * 8;
  float4 u0 = ((const float4*)src)[0];
  float4 u1 = ((const float4*)src)[1];
  float vv[8] = {u0.x, u0.y, u0.z, u0.w, u1.x, u1.y, u1.z, u1.w};
  float s = 0.f;
  bf16x8 h;
#pragma unroll
  for (int j = 0; j < 8; ++j) {
    s = fmaf(vv[j], vv[j], s);
    h[j] = (short)f32_to_bf16_rne(vv[j]);
  }
  s += __shfl_xor(s, 1);
  s += __shfl_xor(s, 2);
  s += __shfl_xor(s, 4);
  s += __shfl_xor(s, 8);
  s += __shfl_xor(s, 16);
  const int slot = 16 * (k & 3) + (k >> 2);
  const int off = slot * 512 + ((m ^ (slot & 7)) << 4);
  *(bf16x8*)(cb + off) = h;
  if (m == 0) c2[k] = s;
}

// Block: 4 waves, 64 rows (16/wave), 64 cols. LDS = 32 KiB (B only).
// __launch_bounds__(256,5): 5 waves/EU -> 5 blocks/CU (5 x 32 KiB = exactly the
// 160 KiB LDS pool), VGPR cap 102 (audited body ~75-90). +25% waves/CU vs R4:
// tests whether delivered BW is marginally parallelism-limited.
// A: global -> registers, depth-2 prefetch over 3 rotating buffer pairs.
__global__ __launch_bounds__(256, 5)
void cluster_q(const float* __restrict__ A, const char* __restrict__ cb,
               const float* __restrict__ c2, float* __restrict__ out) {
  __shared__ char lds[32768];
  const int tid = threadIdx.x;
  const int lane = tid & 63;
  const int w = tid >> 6;
  const int l15 = lane & 15;
  const int g = lane >> 4;
  const long brow = (long)blockIdx.x * 64;

  const char* Ap = (const char*)A + (brow + w * 16 + l15) * 1024 + g * 32;

  // prologue: A prefetch for ks=0,1 (HBM) issued before B stage (L2) so both overlap
  float4 b0a = *(const float4*)(Ap + 0 * 128);
  float4 b0b = *(const float4*)(Ap + 0 * 128 + 16);
  float4 b1a = *(const float4*)(Ap + 1 * 128);
  float4 b1b = *(const float4*)(Ap + 1 * 128 + 16);

  {
    const char* src = cb + w * 8192 + lane * 16;
    char* dst = lds + w * 8192;
#pragma unroll
    for (int i = 0; i < 8; ++i)
      gload16(src + i * 1024, dst + i * 1024);
  }
  __syncthreads();  // B resident (A ks0/ks1 also drained here)

  f32x4 acc[4];
#pragma unroll
  for (int t = 0; t < 4; ++t) acc[t] = (f32x4){0.f, 0.f, 0.f, 0.f};
  float x2l = 0.f;
  float4 b2a, b2b;

#define KSTEP(ks, CA, CB, PA, PB)                                            \
  do {                                                                       \
    float vv[8] = {CA.x, CA.y, CA.z, CA.w, CB.x, CB.y, CB.z, CB.w};          \
    if ((ks) + 2 < 8) {                                                      \
      PA = *(const float4*)(Ap + ((ks) + 2) * 128);                          \
      PB = *(const float4*)(Ap + ((ks) + 2) * 128 + 16);                     \
    }                                                                        \
    bf16x8 af;                                                               \
    _Pragma("unroll") for (int j = 0; j < 8; ++j) {                          \
      x2l = fmaf(vv[j], vv[j], x2l);                                         \
      af[j] = f2bf(vv[j]);                                                   \
    }                                                                        \
    _Pragma("unroll") for (int t = 0; t < 4; ++t) {                          \
      int slot = l15 + 16 * t;                                               \
      bf16x8 bf = *(const bf16x8*)(lds + slot * 512 +                        \
                                   ((((ks) * 4 + g) ^ (slot & 7)) << 4));    \
      acc[t] = __builtin_amdgcn_mfma_f32_16x16x32_bf16(af, bf, acc[t], 0, 0, 0); \
    }                                                                        \
  } while (0)

  // buffers rotate mod 3; prefetch target (ks+2)%3 never aliases ks%3 or (ks+1)%3
  KSTEP(0, b0a, b0b, b2a, b2b);
  KSTEP(1, b1a, b1b, b0a, b0b);
  KSTEP(2, b2a, b2b, b1a, b1b);
  KSTEP(3, b0a, b0b, b2a, b2b);
  KSTEP(4, b1a, b1b, b0a, b0b);
  KSTEP(5, b2a, b2b, b1a, b1b);
  KSTEP(6, b0a, b0b, b0a, b0b);  // ks+2 >= 8: no prefetch
  KSTEP(7, b1a, b1b, b0a, b0b);  // ks+2 >= 8: no prefetch
#undef KSTEP

  // ---- epilogue
  x2l += __shfl_xor(x2l, 16);
  x2l += __shfl_xor(x2l, 32);  // full ||x||^2 for row l15, replicated across g
  float x2r[4];
#pragma unroll
  for (int r = 0; r < 4; ++r) x2r[r] = __shfl(x2l, g * 4 + r);

  float4 c2v = *(const float4*)(c2 + 4 * l15);  // clusters 4*l15 .. +3  (== t)
  float c2a[4] = {c2v.x, c2v.y, c2v.z, c2v.w};

  float qv[4][4];
  float rsum[4] = {0.f, 0.f, 0.f, 0.f};
#pragma unroll
  for (int t = 0; t < 4; ++t) {
#pragma unroll
    for (int r = 0; r < 4; ++r) {
      float d2 = fmaxf(x2r[r] + c2a[t] - 2.0f * acc[t][r], 0.f);
      float qq = __builtin_amdgcn_rcpf(1.0f + d2);  // ALPHA=1, exponent 1
      qv[t][r] = qq;
      rsum[r] += qq;
    }
  }
#pragma unroll
  for (int r = 0; r < 4; ++r) {
    rsum[r] += __shfl_xor(rsum[r], 1);
    rsum[r] += __shfl_xor(rsum[r], 2);
    rsum[r] += __shfl_xor(rsum[r], 4);
    rsum[r] += __shfl_xor(rsum[r], 8);
    float inv = __builtin_amdgcn_rcpf(rsum[r]);
    long orow = brow + w * 16 + g * 4 + r;
    float4 o4 = {qv[0][r] * inv, qv[1][r] * inv, qv[2][r] * inv, qv[3][r] * inv};
    *(float4*)(out + orow * 64 + 4 * l15) = o4;  // lane holds clusters 4*l15..+3
  }
}

extern "C" void kernel_launch(void* const* d_in, const int* in_sizes, int n_in,
                              void* d_out, int out_size, void* d_ws, size_t ws_size,
                              hipStream_t stream) {
  const float* inputs = (const float*)d_in[0];
  const float* clusters = (const float*)d_in[1];
  float* out = (float*)d_out;

  char* cb = (char*)d_ws;                      // 32 KiB pre-swizzled B image
  float* c2 = (float*)((char*)d_ws + 32768);   // 64 floats

  prep_clusters<<<8, 256, 0, stream>>>(clusters, cb, c2);
  cluster_q<<<NPTS / 64, 256, 0, stream>>>(inputs, cb, c2, out);
}